// Round 12
// baseline (139.127 us; speedup 1.0000x reference)
//
#include <hip/hip_runtime.h>

typedef __attribute__((ext_vector_type(8))) _Float16 half8;
typedef __attribute__((ext_vector_type(2))) __fp16 fp16x2;
typedef __attribute__((ext_vector_type(4))) float f32x4;

#define XDIM 8192
#define XOUT 8191
#define TPW 16                     // tiles (of 16 positions) per wave
#define NTILES (1024 * 512)        // 512 tiles per row, 1024 rows
#define NBLOCKS (NTILES / TPW / 4) // 4 waves per block

// 8 halves: elems 0-3 -> k = 4g+j in k-block 0..15, elems 4-7 -> k-block 16..31
// (layout verified on HW: r11 absmax 0.0)
union H8 {
    fp16x2 p[4];
    half8 v;
};

#define MFMA32(A, B, C) __builtin_amdgcn_mfma_f32_16x16x32_f16((A), (B), (C), 0, 0, 0)

__global__ __launch_bounds__(256, 4) void cnn_mfma_kernel(
    const float* __restrict__ rho, const float* __restrict__ w0,
    const float* __restrict__ b0, const float* __restrict__ Wh,
    const float* __restrict__ bh, const float* __restrict__ Wl,
    const float* __restrict__ bl, float* __restrict__ out) {
    const int lane = threadIdx.x & 63;
    const int lm = lane & 15;          // A-row (out ch) / B-col (position) / D-col
    const int kb = (lane >> 4) * 4;    // k-base within block / D row-base

    // ---- per-layer constant A fragments, built once:
    //      A1 = [Whi | Whi]  (multiplies hhi + hlo = h)
    //      A2 = [Wlo | 0  ]  (adds Wlo*hhi compensation term)
    half8 A1_0, A1_1, A1_2, A1_3, A1_4;
    half8 A2_0, A2_1, A2_2, A2_3, A2_4;
#define LOADA(L, A1F, A2F)                                                        \
    {                                                                             \
        float _w0 = (lm < 15 && kb + 0 < 15) ? Wh[(L)*225 + lm*15 + kb + 0] : 0.f;\
        float _w1 = (lm < 15 && kb + 1 < 15) ? Wh[(L)*225 + lm*15 + kb + 1] : 0.f;\
        float _w2 = (lm < 15 && kb + 2 < 15) ? Wh[(L)*225 + lm*15 + kb + 2] : 0.f;\
        float _w3 = (lm < 15 && kb + 3 < 15) ? Wh[(L)*225 + lm*15 + kb + 3] : 0.f;\
        fp16x2 _h01 = __builtin_amdgcn_cvt_pkrtz(_w0, _w1);                       \
        fp16x2 _h23 = __builtin_amdgcn_cvt_pkrtz(_w2, _w3);                       \
        const float _e0 = fmaf(-1.0f, (float)_h01.x, _w0);                        \
        const float _e1 = fmaf(-1.0f, (float)_h01.y, _w1);                        \
        const float _e2 = fmaf(-1.0f, (float)_h23.x, _w2);                        \
        const float _e3 = fmaf(-1.0f, (float)_h23.y, _w3);                        \
        fp16x2 _l01 = __builtin_amdgcn_cvt_pkrtz(_e0, _e1);                       \
        fp16x2 _l23 = __builtin_amdgcn_cvt_pkrtz(_e2, _e3);                       \
        H8 _u1, _u2;                                                              \
        _u1.p[0] = _h01; _u1.p[1] = _h23; _u1.p[2] = _h01; _u1.p[3] = _h23;       \
        fp16x2 _z = __builtin_amdgcn_cvt_pkrtz(0.f, 0.f);                         \
        _u2.p[0] = _l01; _u2.p[1] = _l23; _u2.p[2] = _z;   _u2.p[3] = _z;         \
        A1F = _u1.v;                                                              \
        A2F = _u2.v;                                                              \
    }
    LOADA(0, A1_0, A2_0)
    LOADA(1, A1_1, A2_1)
    LOADA(2, A1_2, A2_2)
    LOADA(3, A1_3, A2_3)
    LOADA(4, A1_4, A2_4)
#undef LOADA

    f32x4 bias0, bias1, bias2, bias3, bias4;   // C-init per layer (rows kb..kb+3)
#define LOADB(L, BV)                                                  \
    {                                                                 \
        (BV).x = (kb + 0 < 15) ? bh[(L)*15 + kb + 0] : 0.f;           \
        (BV).y = (kb + 1 < 15) ? bh[(L)*15 + kb + 1] : 0.f;           \
        (BV).z = (kb + 2 < 15) ? bh[(L)*15 + kb + 2] : 0.f;           \
        (BV).w = (kb + 3 < 15) ? bh[(L)*15 + kb + 3] : 0.f;           \
    }
    LOADB(0, bias0)
    LOADB(1, bias1)
    LOADB(2, bias2)
    LOADB(3, bias3)
    LOADB(4, bias4)
#undef LOADB

    // first-conv weights for this lane's 4 channels (kb..kb+3); ch 15 -> 0
    const float fw0_0 = (kb + 0 < 15) ? w0[2*(kb+0)]   : 0.f;
    const float fw1_0 = (kb + 0 < 15) ? w0[2*(kb+0)+1] : 0.f;
    const float fb_0  = (kb + 0 < 15) ? b0[kb+0]       : 0.f;
    const float fw0_1 = (kb + 1 < 15) ? w0[2*(kb+1)]   : 0.f;
    const float fw1_1 = (kb + 1 < 15) ? w0[2*(kb+1)+1] : 0.f;
    const float fb_1  = (kb + 1 < 15) ? b0[kb+1]       : 0.f;
    const float fw0_2 = (kb + 2 < 15) ? w0[2*(kb+2)]   : 0.f;
    const float fw1_2 = (kb + 2 < 15) ? w0[2*(kb+2)+1] : 0.f;
    const float fb_2  = (kb + 2 < 15) ? b0[kb+2]       : 0.f;
    const float fw0_3 = (kb + 3 < 15) ? w0[2*(kb+3)]   : 0.f;
    const float fw1_3 = (kb + 3 < 15) ? w0[2*(kb+3)+1] : 0.f;
    const float fb_3  = (kb + 3 < 15) ? b0[kb+3]       : 0.f;

    const float wl0 = (kb + 0 < 15) ? Wl[kb + 0] : 0.f;
    const float wl1 = (kb + 1 < 15) ? Wl[kb + 1] : 0.f;
    const float wl2 = (kb + 2 < 15) ? Wl[kb + 2] : 0.f;
    const float wl3 = (kb + 3 < 15) ? Wl[kb + 3] : 0.f;
    const float bl0 = bl[0];

    // ---- each wave owns 16 consecutive tiles of one row ----
    const int wid = blockIdx.x * 4 + (threadIdx.x >> 6);   // 0..32767
    const int brow = wid >> 5;                             // 32 waves per row
    const int xb = ((wid & 31) << 8) + lm;                 // + t*16, t in [0,16)
    const float* rrow = rho + (size_t)brow * XDIM;
    float* orow = out + (size_t)brow * XOUT;

#pragma unroll 4
    for (int t = 0; t < TPW; ++t) {
        const int x = xb + t * 16;                 // <= 8191
        const float r0 = rrow[x];
        const float r1 = rrow[(x < XDIM - 1) ? x + 1 : XDIM - 1];

        // first conv (k=2) + relu, this lane's 4 channels of its position
        float h0 = fmaxf(fmaf(fw0_0, r0, fmaf(fw1_0, r1, fb_0)), 0.f);
        float h1 = fmaxf(fmaf(fw0_1, r0, fmaf(fw1_1, r1, fb_1)), 0.f);
        float h2 = fmaxf(fmaf(fw0_2, r0, fmaf(fw1_2, r1, fb_2)), 0.f);
        float h3 = fmaxf(fmaf(fw0_3, r0, fmaf(fw1_3, r1, fb_3)), 0.f);

        // Per layer: split h into hi/lo, ONE B = [hhi|hlo] in natural register
        // order (zero packing movs); the MFMA's k-block sum gives
        //   A1*B = Whi*hhi + Whi*hlo,  A2*B += Wlo*hhi.
#define HLAYER(A1F, A2F, BV)                                         \
        {                                                            \
            H8 _b;                                                   \
            _b.p[0] = __builtin_amdgcn_cvt_pkrtz(h0, h1);            \
            _b.p[1] = __builtin_amdgcn_cvt_pkrtz(h2, h3);            \
            const float _e0 = fmaf(-1.0f, (float)_b.p[0].x, h0);     \
            const float _e1 = fmaf(-1.0f, (float)_b.p[0].y, h1);     \
            const float _e2 = fmaf(-1.0f, (float)_b.p[1].x, h2);     \
            const float _e3 = fmaf(-1.0f, (float)_b.p[1].y, h3);     \
            _b.p[2] = __builtin_amdgcn_cvt_pkrtz(_e0, _e1);          \
            _b.p[3] = __builtin_amdgcn_cvt_pkrtz(_e2, _e3);          \
            f32x4 _acc = MFMA32((A1F), _b.v, (BV));                  \
            _acc = MFMA32((A2F), _b.v, _acc);                        \
            h0 = fmaxf(_acc.x, 0.f);                                 \
            h1 = fmaxf(_acc.y, 0.f);                                 \
            h2 = fmaxf(_acc.z, 0.f);                                 \
            h3 = fmaxf(_acc.w, 0.f);                                 \
        }
        HLAYER(A1_0, A2_0, bias0)
        HLAYER(A1_1, A2_1, bias1)
        HLAYER(A1_2, A2_2, bias2)
        HLAYER(A1_3, A2_3, bias3)
        HLAYER(A1_4, A2_4, bias4)
#undef HLAYER

        // final dot: partial over this lane's 4 rows (f32), butterfly-sum the
        // 4 lane groups, clip; lanes 0-15 store.
        float s = fmaf(wl0, h0, fmaf(wl1, h1, fmaf(wl2, h2, wl3 * h3)));
        s += __shfl_xor(s, 16, 64);
        s += __shfl_xor(s, 32, 64);
        const float y = fminf(fmaxf(s + bl0, 0.f), 1.f);
        if (lane < 16 && x < XOUT) orow[x] = y;
    }
}

extern "C" void kernel_launch(void* const* d_in, const int* in_sizes, int n_in,
                              void* d_out, int out_size, void* d_ws, size_t ws_size,
                              hipStream_t stream) {
    const float* rho = (const float*)d_in[0];
    const float* w0  = (const float*)d_in[1];
    const float* b0  = (const float*)d_in[2];
    const float* Wh  = (const float*)d_in[3];
    const float* bh  = (const float*)d_in[4];
    const float* Wl  = (const float*)d_in[5];
    const float* bl  = (const float*)d_in[6];
    float* out = (float*)d_out;

    dim3 grid(NBLOCKS);   // 8192 blocks x 4 waves x 16 tiles x 16 pos = 8.39M
    dim3 block(256);
    cnn_mfma_kernel<<<grid, block, 0, stream>>>(rho, w0, b0, Wh, bh, Wl, bl, out);
}